// Round 9
// baseline (306.087 us; speedup 1.0000x reference)
//
#include <hip/hip_runtime.h>
#include <hip/hip_bf16.h>
#include <hip/hip_fp16.h>

typedef unsigned short u16;
typedef short bf16x8_t __attribute__((ext_vector_type(8)));
typedef float f32x4_t  __attribute__((ext_vector_type(4)));

__device__ __forceinline__ u16 f2bf(float f) {
    __hip_bfloat16 h = __float2bfloat16(f);
    union { __hip_bfloat16 b; u16 u; } cv; cv.b = h; return cv.u;
}

__device__ __forceinline__ float bf2f(u16 u) {
    union { unsigned int w; float f; } cv; cv.w = (unsigned int)u << 16; return cv.f;
}

// async global->LDS, 16B per lane; lds dest = wave-uniform base + lane*16
__device__ __forceinline__ void g2l16(const void* g, void* l) {
    __builtin_amdgcn_global_load_lds(
        (const __attribute__((address_space(1))) unsigned int*)g,
        (__attribute__((address_space(3))) unsigned int*)l, 16, 0, 0);
}

// ---------------- merged preprocessing: cast + Wqkv transpose + Wo/W1/W2 transpose ----------------
__global__ __launch_bounds__(256)
void k_prep(const float* __restrict__ x, u16* __restrict__ Xb,
            const float* __restrict__ Wq, const float* __restrict__ Wk,
            const float* __restrict__ Wv, u16* __restrict__ Wqkvt,
            const float* __restrict__ Wo, const float* __restrict__ W1,
            const float* __restrict__ W2, u16* __restrict__ Wot,
            u16* __restrict__ W1t, u16* __restrict__ W2t)
{
    int id = blockIdx.x;
    if (id < 4096) {                                   // cast branch (whole block)
        int i = id * 256 + threadIdx.x;
        float4 f = ((const float4*)x)[i];
        ushort4 o;
        o.x = f2bf(f.x); o.y = f2bf(f.y); o.z = f2bf(f.z); o.w = f2bf(f.w);
        ((ushort4*)Xb)[i] = o;
        return;
    }
    id -= 4096;
    const float* in; u16* out; int R, C, r0, c0;       // in [R][C] -> out [C][R]
    if (id < 768) {                                    // qkvw: id = tx + 16*head + 256*proj
        int zx = id >> 8, hy = (id >> 4) & 15, tx = id & 15;
        in  = (zx == 0 ? Wq : (zx == 1 ? Wk : Wv)) + (size_t)hy * 65536;
        out = Wqkvt + ((size_t)zx * 1024 + hy * 64) * 1024;
        R = 1024; C = 64; r0 = tx * 64; c0 = 0;
    } else {
        id -= 768;
        int tx, ty;
        if (id < 256)       { in = Wo; out = Wot; R = 1024; C = 1024; tx = id & 15; ty = id >> 4; }
        else if (id < 1280) { id -= 256; in = W1; out = W1t; R = 1024; C = 4096; tx = id & 63; ty = id >> 6; }
        else                { id -= 1280; in = W2; out = W2t; R = 4096; C = 1024; tx = id & 15; ty = id >> 4; }
        r0 = ty * 64; c0 = tx * 64;
    }
    __shared__ float t[64][65];
    int lc = threadIdx.x & 63, lr = threadIdx.x >> 6;
#pragma unroll
    for (int p = 0; p < 16; ++p) {
        int rr = p * 4 + lr;
        t[rr][lc] = in[(size_t)(r0 + rr) * C + c0 + lc];
    }
    __syncthreads();
#pragma unroll
    for (int p = 0; p < 16; ++p) {
        int cc = p * 4 + lr;
        out[(size_t)(c0 + cc) * R + r0 + lc] = f2bf(t[lc][cc]);
    }
}

// ---------------- 128x128 bf16 GEMM, split-K -> fp16 partials (O-proj) ----------------
__global__ __launch_bounds__(256, 4)
void k_gemm_bt(const u16* __restrict__ A, const u16* __restrict__ Bt,
               void* __restrict__ out, int M, int N, int K, int kchunk)
{
    __shared__ __align__(16) u16 As[2 * 128 * 32];
    __shared__ __align__(16) u16 Bs[2 * 128 * 32];
    int tid = threadIdx.x;
    int wave = tid >> 6, lane = tid & 63;

    int nx = gridDim.x, nwg = nx * gridDim.y;
    int f  = blockIdx.x + nx * blockIdx.y;
    int f2 = (f & 7) * (nwg >> 3) + (f >> 3);
    int bx = f2 % nx, by = f2 / nx;
    int row0 = by * 128, col0 = bx * 128;

    int z = blockIdx.z;
    int kbeg = z * kchunk;

    int lrow = lane >> 2, lcol = (lane & 3) * 8;
    const u16* pA0 = A  + (size_t)(row0 + wave * 16 + lrow) * K + kbeg + lcol;
    const u16* pA1 = pA0 + (size_t)64 * K;
    const u16* pB0 = Bt + (size_t)(col0 + wave * 16 + lrow) * K + kbeg + lcol;
    const u16* pB1 = pB0 + (size_t)64 * K;
    u16* lA0 = &As[wave * 512];
    u16* lA1 = &As[2048 + wave * 512];
    u16* lB0 = &Bs[wave * 512];
    u16* lB1 = &Bs[2048 + wave * 512];

    int wm = (wave >> 1) * 64, wn = (wave & 1) * 64;
    int quad = lane >> 4, l16 = lane & 15;

    f32x4_t acc[4][4];
#pragma unroll
    for (int i = 0; i < 4; i++)
#pragma unroll
        for (int j = 0; j < 4; j++) acc[i][j] = f32x4_t{0.f, 0.f, 0.f, 0.f};

    for (int kk = 0; kk < kchunk; kk += 64) {
        __syncthreads();
        g2l16(pA0, lA0);      g2l16(pA1, lA1);
        g2l16(pA0 + 32, lA0 + 4096); g2l16(pA1 + 32, lA1 + 4096);
        g2l16(pB0, lB0);      g2l16(pB1, lB1);
        g2l16(pB0 + 32, lB0 + 4096); g2l16(pB1 + 32, lB1 + 4096);
        pA0 += 64; pA1 += 64; pB0 += 64; pB1 += 64;
        __syncthreads();

#pragma unroll
        for (int s = 0; s < 2; ++s) {
            const u16* as = &As[s * 4096];
            const u16* bs = &Bs[s * 4096];
            bf16x8_t a[4], b[4];
#pragma unroll
            for (int i = 0; i < 4; ++i)
                a[i] = *(const bf16x8_t*)&as[(wm + i * 16 + l16) * 32 + quad * 8];
#pragma unroll
            for (int j = 0; j < 4; ++j)
                b[j] = *(const bf16x8_t*)&bs[(wn + j * 16 + l16) * 32 + quad * 8];
#pragma unroll
            for (int i = 0; i < 4; ++i)
#pragma unroll
                for (int j = 0; j < 4; ++j)
                    acc[i][j] = __builtin_amdgcn_mfma_f32_16x16x32_bf16(a[i], b[j], acc[i][j], 0, 0, 0);
        }
    }

#pragma unroll
    for (int i = 0; i < 4; ++i)
#pragma unroll
        for (int j = 0; j < 4; ++j)
#pragma unroll
            for (int r = 0; r < 4; ++r) {
                int row = row0 + wm + i * 16 + quad * 4 + r;
                int col = col0 + wn + j * 16 + l16;
                ((__half*)out)[(size_t)z * M * N + (size_t)row * N + col] =
                    __float2half(acc[i][j][r]);
            }
}

// ================= common 256x128 bf16 GEMM body (2-phase, 512 thr, 8 waves) =================
// EPI 0: fp16 split-K partial; EPI 1: relu+bias bf16
template<int EPI>
__device__ __forceinline__
void gemm256x128(const u16* __restrict__ A, const u16* __restrict__ Bt,
                 const float* __restrict__ bias0, void* __restrict__ out,
                 int M, int N, int K, int kchunk, int z, int bx, int by)
{
    __shared__ __align__(16) u16 As[2 * 256 * 32];   // 2 subtiles of [256][32]
    __shared__ __align__(16) u16 Bs[2 * 128 * 32];   // 2 subtiles of [128][32]
    int tid = threadIdx.x;
    int wave = tid >> 6, lane = tid & 63;
    int row0 = by * 256, col0 = bx * 128;
    int kbeg = z * kchunk;

    int lrow = lane >> 2, lcol = (lane & 3) * 8;
    const u16* pA0 = A  + (size_t)(row0 + wave * 16 + lrow) * K + kbeg + lcol;  // rows 0..127
    const u16* pA1 = pA0 + (size_t)128 * K;                                     // rows 128..255
    const u16* pB0 = Bt + (size_t)(col0 + wave * 16 + lrow) * K + kbeg + lcol;  // rows 0..127
    u16* lA0 = &As[wave * 512];
    u16* lA1 = &As[4096 + wave * 512];
    u16* lB0 = &Bs[wave * 512];

    int wm = (wave >> 1) * 64, wn = (wave & 1) * 64;
    int quad = lane >> 4, l16 = lane & 15;

    f32x4_t acc[4][4];
#pragma unroll
    for (int i = 0; i < 4; i++)
#pragma unroll
        for (int j = 0; j < 4; j++) acc[i][j] = f32x4_t{0.f, 0.f, 0.f, 0.f};

    for (int kk = 0; kk < kchunk; kk += 64) {
        __syncthreads();
        g2l16(pA0, lA0);           g2l16(pA1, lA1);
        g2l16(pA0 + 32, lA0 + 8192); g2l16(pA1 + 32, lA1 + 8192);
        g2l16(pB0, lB0);           g2l16(pB0 + 32, lB0 + 4096);
        pA0 += 64; pA1 += 64; pB0 += 64;
        __syncthreads();

#pragma unroll
        for (int s = 0; s < 2; ++s) {
            const u16* as = &As[s * 8192];
            const u16* bs = &Bs[s * 4096];
            bf16x8_t a[4], b[4];
#pragma unroll
            for (int i = 0; i < 4; ++i)
                a[i] = *(const bf16x8_t*)&as[(wm + i * 16 + l16) * 32 + quad * 8];
#pragma unroll
            for (int j = 0; j < 4; ++j)
                b[j] = *(const bf16x8_t*)&bs[(wn + j * 16 + l16) * 32 + quad * 8];
#pragma unroll
            for (int i = 0; i < 4; ++i)
#pragma unroll
                for (int j = 0; j < 4; ++j)
                    acc[i][j] = __builtin_amdgcn_mfma_f32_16x16x32_bf16(a[i], b[j], acc[i][j], 0, 0, 0);
        }
    }

#pragma unroll
    for (int i = 0; i < 4; ++i)
#pragma unroll
        for (int j = 0; j < 4; ++j)
#pragma unroll
            for (int r = 0; r < 4; ++r) {
                int row = row0 + wm + i * 16 + quad * 4 + r;
                int col = col0 + wn + j * 16 + l16;
                float v = acc[i][j][r];
                if (EPI == 0) {
                    ((__half*)out)[(size_t)z * M * N + (size_t)row * N + col] = __float2half(v);
                } else {
                    ((u16*)out)[(size_t)row * N + col] = f2bf(fmaxf(v + bias0[col], 0.f));
                }
            }
}

// ================= QKV GEMM (256x128) =================
// Q/K blocks: direct per-element scatter to [bh][s][dk] (R5-measured path, no LDS epilogue).
// V blocks: LDS restage TRANSPOSED (tile2[c][r], LD=136) -> vectorized row reads -> VT[bh][dk][s].
// Coverage check (R8 bugfix): 512 thr x 4 uint4 x 16B = 32KB = full 128x128 half-tile.
__global__ __launch_bounds__(512, 4)
void k_gemm_qkv(const u16* __restrict__ A, const u16* __restrict__ Bt,
                const float* __restrict__ bq, const float* __restrict__ bk,
                const float* __restrict__ bv, u16* __restrict__ QK,
                u16* __restrict__ VT, int M, int N, int K)
{
    __shared__ __align__(16) char pool[49152];
    u16* As = (u16*)pool;                 // 32KB: 2 subtiles [256][32]
    u16* Bs = (u16*)(pool + 32768);       // 16KB: 2 subtiles [128][32]

    int tid = threadIdx.x;
    int wave = tid >> 6, lane = tid & 63;

    // XCD-chunked bijective swizzle (nwg = 24*16 = 384, 384 % 8 == 0)
    int nx = gridDim.x, nwg = nx * gridDim.y;
    int f  = blockIdx.x + nx * blockIdx.y;
    int f2 = (f & 7) * (nwg >> 3) + (f >> 3);
    int bx = f2 % nx, by = f2 / nx;
    int row0 = by * 256, col0 = bx * 128;

    int lrow = lane >> 2, lcol = (lane & 3) * 8;
    const u16* pA0 = A  + (size_t)(row0 + wave * 16 + lrow) * K + lcol;
    const u16* pA1 = pA0 + (size_t)128 * K;
    const u16* pB0 = Bt + (size_t)(col0 + wave * 16 + lrow) * K + lcol;
    u16* lA0 = As + wave * 512;
    u16* lA1 = As + 4096 + wave * 512;
    u16* lB0 = Bs + wave * 512;

    int wm = (wave >> 1) * 64, wn = (wave & 1) * 64;
    int quad = lane >> 4, l16 = lane & 15;

    f32x4_t acc[4][4];
#pragma unroll
    for (int i = 0; i < 4; i++)
#pragma unroll
        for (int j = 0; j < 4; j++) acc[i][j] = f32x4_t{0.f, 0.f, 0.f, 0.f};

    for (int kk = 0; kk < K; kk += 64) {
        __syncthreads();
        g2l16(pA0, lA0);           g2l16(pA1, lA1);
        g2l16(pA0 + 32, lA0 + 8192); g2l16(pA1 + 32, lA1 + 8192);
        g2l16(pB0, lB0);           g2l16(pB0 + 32, lB0 + 4096);
        pA0 += 64; pA1 += 64; pB0 += 64;
        __syncthreads();

#pragma unroll
        for (int s = 0; s < 2; ++s) {
            const u16* as = As + s * 8192;
            const u16* bs = Bs + s * 4096;
            bf16x8_t a[4], b[4];
#pragma unroll
            for (int i = 0; i < 4; ++i)
                a[i] = *(const bf16x8_t*)(as + (wm + i * 16 + l16) * 32 + quad * 8);
#pragma unroll
            for (int j = 0; j < 4; ++j)
                b[j] = *(const bf16x8_t*)(bs + (wn + j * 16 + l16) * 32 + quad * 8);
#pragma unroll
            for (int i = 0; i < 4; ++i)
#pragma unroll
                for (int j = 0; j < 4; ++j)
                    acc[i][j] = __builtin_amdgcn_mfma_f32_16x16x32_bf16(a[i], b[j], acc[i][j], 0, 0, 0);
        }
    }

    int proj = col0 >> 10;                    // uniform per block (1024 % 128 == 0)
    int h0   = (col0 & 1023) >> 6;            // first of 2 heads in this tile
    int b_   = row0 >> 10, sb = row0 & 1023;  // batch, s-base

    if (proj < 2) {
        // ---- Q/K: direct scatter (32B-granular, measured-good; no LDS, no barriers) ----
        const float* bp = proj == 0 ? bq : bk;
        float scale = proj == 0 ? 0.18033688f : 1.f;   // 0.125 * log2(e)
        u16* dstbase = QK + (size_t)proj * 4194304;
#pragma unroll
        for (int i = 0; i < 4; ++i)
#pragma unroll
            for (int j = 0; j < 4; ++j)
#pragma unroll
                for (int r = 0; r < 4; ++r) {
                    int row = row0 + wm + i * 16 + quad * 4 + r;
                    int col = col0 + wn + j * 16 + l16;
                    int within = col & 1023;
                    float v = (acc[i][j][r] + bp[within]) * scale;
                    int h = within >> 6, kq = within & 63;
                    int s_ = row & 1023;
                    size_t bh = (size_t)((b_ << 4) + h);
                    dstbase[bh * 65536 + ((size_t)s_ << 6) + kq] = f2bf(v);
                }
    } else {
        // ---- V: transposed restage -> coalesced VT ----
        u16* tile = (u16*)pool;               // tile2[c(128)][r(128)] LD=136, 34816B
        int rbase = wm & 127;
        int myhalf = wave >> 2;
        __syncthreads();                      // retire K-loop LDS
#pragma unroll
        for (int hh = 0; hh < 2; ++hh) {
            if (myhalf == hh) {
#pragma unroll
                for (int i = 0; i < 4; ++i)
#pragma unroll
                    for (int j = 0; j < 4; ++j) {
                        int c = wn + j * 16 + l16;
                        int bcol = (col0 & 1023) + c;
#pragma unroll
                        for (int r = 0; r < 4; ++r)
                            tile[c * 136 + rbase + i * 16 + quad * 4 + r] =
                                f2bf(acc[i][j][r] + bv[bcol]);
                    }
            }
            __syncthreads();
            // row reads: 4 consecutive uint4 per thread (full coverage: 512*4*16B = 32KB)
            int c = tid >> 2, v0 = (tid & 3) * 4;  // c in 0..127, slots v0..v0+3 of 16
            int head = c >> 6, kq = c & 63;
            size_t bh = (size_t)(b_ * 16 + h0 + head);
            u16* vb = VT + bh * 65536 + (size_t)kq * 1024 + sb + hh * 128;
#pragma unroll
            for (int k = 0; k < 4; ++k) {
                uint4 x = *(const uint4*)&tile[c * 136 + (v0 + k) * 8];
                *(uint4*)&vb[(v0 + k) * 8] = x;
            }
            __syncthreads();
        }
    }
}

// distinct-named wrappers for profiler decomposition (XCD-swizzled: nwg%8==0)
__global__ __launch_bounds__(512, 4)
void k_gemm_ffn1(const u16* __restrict__ A, const u16* __restrict__ Bt,
                 const float* __restrict__ b1, void* __restrict__ out,
                 int M, int N, int K)
{
    int nx = gridDim.x, nwg = nx * gridDim.y;
    int f  = blockIdx.x + nx * blockIdx.y;
    int f2 = (f & 7) * (nwg >> 3) + (f >> 3);
    gemm256x128<1>(A, Bt, b1, out, M, N, K, K, 0, f2 % nx, f2 / nx);
}

// FFN2: split-K=4, fp16 partials, XCD-chunked bijective swizzle within each z-slice
__global__ __launch_bounds__(512, 4)
void k_gemm_ffn2(const u16* __restrict__ A, const u16* __restrict__ Bt,
                 void* __restrict__ out, int M, int N, int K, int kchunk)
{
    int nx = gridDim.x, nwg = nx * gridDim.y;
    int f  = blockIdx.x + nx * blockIdx.y;
    int f2 = (f & 7) * (nwg >> 3) + (f >> 3);
    gemm256x128<0>(A, Bt, nullptr, out, M, N, K, kchunk, blockIdx.z, f2 % nx, f2 / nx);
}

// ---------------- flash attention v3: dbuf K/V, single barrier/tile, setprio ----------------
__global__ __launch_bounds__(512, 4)
void k_attn(const u16* __restrict__ Qg, const u16* __restrict__ Kg,
            const u16* __restrict__ VTg, u16* __restrict__ Og)
{
    __shared__ __align__(16) u16 Ks[2][64 * 64];
    __shared__ __align__(16) u16 Vs[2][64 * 64];
    __shared__ __align__(16) u16 Ps[128 * 64];

    int tid = threadIdx.x, wave = tid >> 6, lane = tid & 63;
    int quad = lane >> 4, l16 = lane & 15;

    int f  = blockIdx.x + gridDim.x * blockIdx.y;
    int f2 = (f & 7) * ((gridDim.x * gridDim.y) >> 3) + (f >> 3);
    int bh = f2 >> 3;
    int q0 = (f2 & 7) * 128;
    int wrow = wave * 16;

    const u16* Qp  = Qg  + (size_t)bh * 65536;
    const u16* Kp  = Kg  + (size_t)bh * 65536;
    const u16* VTp = VTg + (size_t)bh * 65536;

    int arow_g = q0 + wrow + l16;
    bf16x8_t aq0 = *(const bf16x8_t*)&Qp[(size_t)arow_g * 64 + quad * 8];
    bf16x8_t aq1 = *(const bf16x8_t*)&Qp[(size_t)arow_g * 64 + 32 + quad * 8];

    int srow = tid >> 3, scb = tid & 7;
    int sdoff = srow * 64 + ((scb ^ (srow & 7)) * 8);

    uint4 kreg = *(const uint4*)&Kp[(size_t)srow * 64 + scb * 8];
    uint4 vreg = *(const uint4*)&VTp[(size_t)srow * 1024 + scb * 8];

    f32x4_t o[4], lsum;
#pragma unroll
    for (int nt = 0; nt < 4; ++nt) o[nt] = f32x4_t{0.f, 0.f, 0.f, 0.f};
    lsum = f32x4_t{0.f, 0.f, 0.f, 0.f};

    bf16x8_t ones;
#pragma unroll
    for (int j = 0; j < 8; ++j) ones[j] = (short)0x3F80;

    int a7 = l16 & 7;

    *(uint4*)&Ks[0][sdoff] = kreg;
    *(uint4*)&Vs[0][sdoff] = vreg;
    kreg = *(const uint4*)&Kp[(size_t)(64 + srow) * 64 + scb * 8];
    vreg = *(const uint4*)&VTp[(size_t)srow * 1024 + 64 + scb * 8];
    __syncthreads();

    for (int t = 0; t < 16; ++t) {
        int cur = t & 1, nxt = cur ^ 1;
        if (t < 15) {
            *(uint4*)&Ks[nxt][sdoff] = kreg;
            *(uint4*)&Vs[nxt][sdoff] = vreg;
        }
        if (t < 14) {
            kreg = *(const uint4*)&Kp[(size_t)((t + 2) * 64 + srow) * 64 + scb * 8];
            vreg = *(const uint4*)&VTp[(size_t)srow * 1024 + (t + 2) * 64 + scb * 8];
        }

        f32x4_t s[4];
        __builtin_amdgcn_s_setprio(1);
#pragma unroll
        for (int nt = 0; nt < 4; ++nt) {
            int brow = nt * 16 + l16;
            bf16x8_t bk0 = *(const bf16x8_t*)&Ks[cur][brow * 64 + ((quad ^ a7) * 8)];
            bf16x8_t bk1 = *(const bf16x8_t*)&Ks[cur][brow * 64 + (((4 + quad) ^ a7) * 8)];
            s[nt] = __builtin_amdgcn_mfma_f32_16x16x32_bf16(aq0, bk0, f32x4_t{0.f,0.f,0.f,0.f}, 0, 0, 0);
            s[nt] = __builtin_amdgcn_mfma_f32_16x16x32_bf16(aq1, bk1, s[nt], 0, 0, 0);
        }
        __builtin_amdgcn_s_setprio(0);

#pragma unroll
        for (int nt = 0; nt < 4; ++nt) {
            int pcb = nt * 2 + (l16 >> 3);
#pragma unroll
            for (int r = 0; r < 4; ++r) {
                float p = exp2f(s[nt][r]);
                int pr = wrow + quad * 4 + r;
                Ps[pr * 64 + ((pcb ^ (pr & 7)) * 8) + (l16 & 7)] = f2bf(p);
            }
        }

        int arow = wrow + l16;
        bf16x8_t ap0 = *(const bf16x8_t*)&Ps[arow * 64 + ((quad ^ a7) * 8)];
        bf16x8_t ap1 = *(const bf16x8_t*)&Ps[arow * 64 + (((4 + quad) ^ a7) * 8)];
        __builtin_amdgcn_s_setprio(1);
#pragma unroll
        for (int nt = 0; nt < 4; ++nt) {
            int vrow = nt * 16 + l16;
            bf16x8_t bv0 = *(const bf16x8_t*)&Vs[cur][vrow * 64 + ((quad ^ a7) * 8)];
            bf16x8_t bv1 = *(const bf16x8_t*)&Vs[cur][vrow * 64 + (((4 + quad) ^ a7) * 8)];
            o[nt] = __builtin_amdgcn_mfma_f32_16x16x32_bf16(ap0, bv0, o[nt], 0, 0, 0);
            o[nt] = __builtin_amdgcn_mfma_f32_16x16x32_bf16(ap1, bv1, o[nt], 0, 0, 0);
        }
        lsum = __builtin_amdgcn_mfma_f32_16x16x32_bf16(ap0, ones, lsum, 0, 0, 0);
        lsum = __builtin_amdgcn_mfma_f32_16x16x32_bf16(ap1, ones, lsum, 0, 0, 0);
        __builtin_amdgcn_s_setprio(0);
        __syncthreads();
    }

    int b = bh >> 4, h = bh & 15;
    float invl[4];
#pragma unroll
    for (int r = 0; r < 4; ++r) invl[r] = 1.f / lsum[r];
#pragma unroll
    for (int nt = 0; nt < 4; ++nt)
#pragma unroll
        for (int r = 0; r < 4; ++r) {
            int srow2 = q0 + wrow + quad * 4 + r;
            Og[(size_t)(b * 1024 + srow2) * 1024 + (h << 6) + nt * 16 + l16] = f2bf(o[nt][r] * invl[r]);
        }
}

// ---------------- LayerNorm over (sum of NP fp16 partials + bias) + residual ----------------
template<int MODE, int NP>
__global__ __launch_bounds__(256)
void k_ln2(const __half* __restrict__ p, const float* __restrict__ bias,
           const float* __restrict__ residf, const u16* __restrict__ residb,
           const float* __restrict__ g, const float* __restrict__ be,
           float* __restrict__ out, u16* __restrict__ outb)
{
    int row = blockIdx.x, tid = threadIdx.x;
    size_t base = (size_t)row * 1024;
    int c0 = tid * 4;
    float xv[4];
    {
        float4 b4 = *(const float4*)&bias[c0];
        xv[0] = b4.x; xv[1] = b4.y; xv[2] = b4.z; xv[3] = b4.w;
    }
#pragma unroll
    for (int z = 0; z < NP; ++z) {
        union { uint2 u; __half h[4]; } cv;
        cv.u = *(const uint2*)&p[(size_t)z * 4194304 + base + c0];
#pragma unroll
        for (int i = 0; i < 4; ++i) xv[i] += __half2float(cv.h[i]);
    }
    float s = 0.f, sq = 0.f;
#pragma unroll
    for (int i = 0; i < 4; ++i) { s += xv[i]; sq += xv[i] * xv[i]; }
#pragma unroll
    for (int off = 32; off; off >>= 1) { s += __shfl_down(s, off); sq += __shfl_down(sq, off); }
    __shared__ float ss[4], ssq[4];
    int wv = tid >> 6;
    if ((tid & 63) == 0) { ss[wv] = s; ssq[wv] = sq; }
    __syncthreads();
    s  = ss[0] + ss[1] + ss[2] + ss[3];
    sq = ssq[0] + ssq[1] + ssq[2] + ssq[3];
    float mean = s * (1.f / 1024.f);
    float var  = sq * (1.f / 1024.f) - mean * mean;
    float rstd = rsqrtf(var + 1e-5f);

    float4 g4  = *(const float4*)&g[c0];
    float4 be4 = *(const float4*)&be[c0];
    float gv[4] = {g4.x, g4.y, g4.z, g4.w};
    float bv[4] = {be4.x, be4.y, be4.z, be4.w};
    float rv[4];
    if (MODE == 0) {
        float4 r4 = *(const float4*)&residf[base + c0];
        rv[0] = r4.x; rv[1] = r4.y; rv[2] = r4.z; rv[3] = r4.w;
    } else {
        ushort4 rb = *(const ushort4*)&residb[base + c0];
        rv[0] = bf2f(rb.x); rv[1] = bf2f(rb.y); rv[2] = bf2f(rb.z); rv[3] = bf2f(rb.w);
    }
    float y[4];
#pragma unroll
    for (int i = 0; i < 4; ++i) y[i] = rv[i] + (xv[i] - mean) * rstd * gv[i] + bv[i];
    if (MODE == 0) {
        ushort4 o;
        o.x = f2bf(y[0]); o.y = f2bf(y[1]); o.z = f2bf(y[2]); o.w = f2bf(y[3]);
        *(ushort4*)&outb[base + c0] = o;
    } else {
        float4 o; o.x = y[0]; o.y = y[1]; o.z = y[2]; o.w = y[3];
        *(float4*)&out[base + c0] = o;
    }
}

extern "C" void kernel_launch(void* const* d_in, const int* in_sizes, int n_in,
                              void* d_out, int out_size, void* d_ws, size_t ws_size,
                              hipStream_t stream) {
    const float* x   = (const float*)d_in[0];
    const float* Wq  = (const float*)d_in[1];
    const float* bq  = (const float*)d_in[2];
    const float* Wk  = (const float*)d_in[3];
    const float* bk  = (const float*)d_in[4];
    const float* Wv  = (const float*)d_in[5];
    const float* bv  = (const float*)d_in[6];
    const float* Wo  = (const float*)d_in[7];
    const float* bo  = (const float*)d_in[8];
    const float* W1  = (const float*)d_in[9];
    const float* b1  = (const float*)d_in[10];
    const float* W2  = (const float*)d_in[11];
    const float* b2  = (const float*)d_in[12];
    const float* g1  = (const float*)d_in[13];
    const float* be1 = (const float*)d_in[14];
    const float* g2  = (const float*)d_in[15];
    const float* be2 = (const float*)d_in[16];
    float* out = (float*)d_out;

    char* w = (char*)d_ws;
    u16*    Xb    = (u16*)(w);                    //  8 MB bf16 x (A operand; live through QKV)
    u16*    Wqkvt = (u16*)(w + 8388608);          //  6 MB [3072,1024] B^T
    u16*    Wot   = (u16*)(w + 14680064);         //  2 MB
    u16*    W1t   = (u16*)(w + 16777216);         //  8 MB
    u16*    W2t   = (u16*)(w + 25165824);         //  8 MB
    u16*    Qb    = (u16*)(w + 33554432);         //  8 MB [BH,S,DK] (K at +8MB)
    u16*    VTb   = (u16*)(w + 50331648);         //  8 MB [BH,DK,S] written by QKV epilogue
    u16*    Oc    = (u16*)(w + 58720256);         //  8 MB [4096,1024]
    __half* part4 = (__half*)(w + 33554432);      // 32 MB FFN2 split-K=4 fp16 partials (dead Q/K/VT/Oc)
    __half* part2 = (__half*)(w + 67108864);      // 16 MB O-proj split-K=2 fp16 partials
    u16*    x1b   = (u16*)(w + 117440512);        //  8 MB
    u16*    hb    = (u16*)(w + 125829120);        // 32 MB [4096,4096]

    // merged cast + all weight transposes (one launch)
    k_prep<<<7168, 256, 0, stream>>>(x, Xb, Wq, Wk, Wv, Wqkvt, Wo, W1, W2, Wot, W1t, W2t);

    // fused QKV projection; V written directly transposed
    k_gemm_qkv<<<dim3(24, 16), 512, 0, stream>>>(Xb, Wqkvt, bq, bk, bv, Qb, VTb, 4096, 3072, 1024);

    // flash attention v3 (dbuf K/V single-barrier)
    k_attn<<<dim3(8, 64), 512, 0, stream>>>(Qb, Qb + 4194304, VTb, Oc);

    // output projection, split-K=2, fp16 partials (128x128 kernel)
    k_gemm_bt<<<dim3(8, 32, 2), 256, 0, stream>>>(Oc, Wot, part2, 4096, 1024, 1024, 512);

    // x1b = bf16(x + LN(part0+part1+bo))
    k_ln2<0, 2><<<4096, 256, 0, stream>>>(part2, bo, x, nullptr, g1, be1, nullptr, x1b);

    // FFN1 (256x128 tile, 2-phase, XCD-swizzled): hb = relu(x1b @ W1 + b1)
    k_gemm_ffn1<<<dim3(32, 16), 512, 0, stream>>>(x1b, W1t, b1, hb, 4096, 4096, 1024);

    // FFN2 (256x128 tile, 2-phase), split-K=4, fp16 partials
    k_gemm_ffn2<<<dim3(8, 16, 4), 512, 0, stream>>>(hb, W2t, part4, 4096, 1024, 4096, 1024);

    // out = x1b + LN(part0..3 + b2)
    k_ln2<1, 4><<<4096, 256, 0, stream>>>(part4, b2, nullptr, x1b, g2, be2, out, nullptr);
}

// Round 10
// 303.588 us; speedup vs baseline: 1.0082x; 1.0082x over previous
//
#include <hip/hip_runtime.h>
#include <hip/hip_bf16.h>
#include <hip/hip_fp16.h>

typedef unsigned short u16;
typedef short bf16x8_t __attribute__((ext_vector_type(8)));
typedef float f32x4_t  __attribute__((ext_vector_type(4)));

__device__ __forceinline__ u16 f2bf(float f) {
    __hip_bfloat16 h = __float2bfloat16(f);
    union { __hip_bfloat16 b; u16 u; } cv; cv.b = h; return cv.u;
}

__device__ __forceinline__ float bf2f(u16 u) {
    union { unsigned int w; float f; } cv; cv.w = (unsigned int)u << 16; return cv.f;
}

// async global->LDS, 16B per lane; lds dest = wave-uniform base + lane*16
__device__ __forceinline__ void g2l16(const void* g, void* l) {
    __builtin_amdgcn_global_load_lds(
        (const __attribute__((address_space(1))) unsigned int*)g,
        (__attribute__((address_space(3))) unsigned int*)l, 16, 0, 0);
}

// ---------------- merged preprocessing: cast + Wqkv transpose + Wo/W1/W2 transpose ----------------
__global__ __launch_bounds__(256)
void k_prep(const float* __restrict__ x, u16* __restrict__ Xb,
            const float* __restrict__ Wq, const float* __restrict__ Wk,
            const float* __restrict__ Wv, u16* __restrict__ Wqkvt,
            const float* __restrict__ Wo, const float* __restrict__ W1,
            const float* __restrict__ W2, u16* __restrict__ Wot,
            u16* __restrict__ W1t, u16* __restrict__ W2t)
{
    int id = blockIdx.x;
    if (id < 4096) {                                   // cast branch (whole block)
        int i = id * 256 + threadIdx.x;
        float4 f = ((const float4*)x)[i];
        ushort4 o;
        o.x = f2bf(f.x); o.y = f2bf(f.y); o.z = f2bf(f.z); o.w = f2bf(f.w);
        ((ushort4*)Xb)[i] = o;
        return;
    }
    id -= 4096;
    const float* in; u16* out; int R, C, r0, c0;       // in [R][C] -> out [C][R]
    if (id < 768) {                                    // qkvw: id = tx + 16*head + 256*proj
        int zx = id >> 8, hy = (id >> 4) & 15, tx = id & 15;
        in  = (zx == 0 ? Wq : (zx == 1 ? Wk : Wv)) + (size_t)hy * 65536;
        out = Wqkvt + ((size_t)zx * 1024 + hy * 64) * 1024;
        R = 1024; C = 64; r0 = tx * 64; c0 = 0;
    } else {
        id -= 768;
        int tx, ty;
        if (id < 256)       { in = Wo; out = Wot; R = 1024; C = 1024; tx = id & 15; ty = id >> 4; }
        else if (id < 1280) { id -= 256; in = W1; out = W1t; R = 1024; C = 4096; tx = id & 63; ty = id >> 6; }
        else                { id -= 1280; in = W2; out = W2t; R = 4096; C = 1024; tx = id & 15; ty = id >> 4; }
        r0 = ty * 64; c0 = tx * 64;
    }
    __shared__ float t[64][65];
    int lc = threadIdx.x & 63, lr = threadIdx.x >> 6;
#pragma unroll
    for (int p = 0; p < 16; ++p) {
        int rr = p * 4 + lr;
        t[rr][lc] = in[(size_t)(r0 + rr) * C + c0 + lc];
    }
    __syncthreads();
#pragma unroll
    for (int p = 0; p < 16; ++p) {
        int cc = p * 4 + lr;
        out[(size_t)(c0 + cc) * R + r0 + lc] = f2bf(t[lc][cc]);
    }
}

// ---------------- 128x128 bf16 GEMM, split-K -> fp16 partials (O-proj) ----------------
__global__ __launch_bounds__(256, 4)
void k_gemm_bt(const u16* __restrict__ A, const u16* __restrict__ Bt,
               void* __restrict__ out, int M, int N, int K, int kchunk)
{
    __shared__ __align__(16) u16 As[2 * 128 * 32];
    __shared__ __align__(16) u16 Bs[2 * 128 * 32];
    int tid = threadIdx.x;
    int wave = tid >> 6, lane = tid & 63;

    int nx = gridDim.x, nwg = nx * gridDim.y;
    int f  = blockIdx.x + nx * blockIdx.y;
    int f2 = (f & 7) * (nwg >> 3) + (f >> 3);
    int bx = f2 % nx, by = f2 / nx;
    int row0 = by * 128, col0 = bx * 128;

    int z = blockIdx.z;
    int kbeg = z * kchunk;

    int lrow = lane >> 2, lcol = (lane & 3) * 8;
    const u16* pA0 = A  + (size_t)(row0 + wave * 16 + lrow) * K + kbeg + lcol;
    const u16* pA1 = pA0 + (size_t)64 * K;
    const u16* pB0 = Bt + (size_t)(col0 + wave * 16 + lrow) * K + kbeg + lcol;
    const u16* pB1 = pB0 + (size_t)64 * K;
    u16* lA0 = &As[wave * 512];
    u16* lA1 = &As[2048 + wave * 512];
    u16* lB0 = &Bs[wave * 512];
    u16* lB1 = &Bs[2048 + wave * 512];

    int wm = (wave >> 1) * 64, wn = (wave & 1) * 64;
    int quad = lane >> 4, l16 = lane & 15;

    f32x4_t acc[4][4];
#pragma unroll
    for (int i = 0; i < 4; i++)
#pragma unroll
        for (int j = 0; j < 4; j++) acc[i][j] = f32x4_t{0.f, 0.f, 0.f, 0.f};

    for (int kk = 0; kk < kchunk; kk += 64) {
        __syncthreads();
        g2l16(pA0, lA0);      g2l16(pA1, lA1);
        g2l16(pA0 + 32, lA0 + 4096); g2l16(pA1 + 32, lA1 + 4096);
        g2l16(pB0, lB0);      g2l16(pB1, lB1);
        g2l16(pB0 + 32, lB0 + 4096); g2l16(pB1 + 32, lB1 + 4096);
        pA0 += 64; pA1 += 64; pB0 += 64; pB1 += 64;
        __syncthreads();

#pragma unroll
        for (int s = 0; s < 2; ++s) {
            const u16* as = &As[s * 4096];
            const u16* bs = &Bs[s * 4096];
            bf16x8_t a[4], b[4];
#pragma unroll
            for (int i = 0; i < 4; ++i)
                a[i] = *(const bf16x8_t*)&as[(wm + i * 16 + l16) * 32 + quad * 8];
#pragma unroll
            for (int j = 0; j < 4; ++j)
                b[j] = *(const bf16x8_t*)&bs[(wn + j * 16 + l16) * 32 + quad * 8];
#pragma unroll
            for (int i = 0; i < 4; ++i)
#pragma unroll
                for (int j = 0; j < 4; ++j)
                    acc[i][j] = __builtin_amdgcn_mfma_f32_16x16x32_bf16(a[i], b[j], acc[i][j], 0, 0, 0);
        }
    }

#pragma unroll
    for (int i = 0; i < 4; ++i)
#pragma unroll
        for (int j = 0; j < 4; ++j)
#pragma unroll
            for (int r = 0; r < 4; ++r) {
                int row = row0 + wm + i * 16 + quad * 4 + r;
                int col = col0 + wn + j * 16 + l16;
                ((__half*)out)[(size_t)z * M * N + (size_t)row * N + col] =
                    __float2half(acc[i][j][r]);
            }
}

// ================= common 256x128 bf16 GEMM body (2-phase, 512 thr, 8 waves) =================
// EPI 0: fp16 split-K partial; EPI 1: relu+bias bf16
template<int EPI>
__device__ __forceinline__
void gemm256x128(const u16* __restrict__ A, const u16* __restrict__ Bt,
                 const float* __restrict__ bias0, void* __restrict__ out,
                 int M, int N, int K, int kchunk, int z, int bx, int by)
{
    __shared__ __align__(16) u16 As[2 * 256 * 32];   // 2 subtiles of [256][32]
    __shared__ __align__(16) u16 Bs[2 * 128 * 32];   // 2 subtiles of [128][32]
    int tid = threadIdx.x;
    int wave = tid >> 6, lane = tid & 63;
    int row0 = by * 256, col0 = bx * 128;
    int kbeg = z * kchunk;

    int lrow = lane >> 2, lcol = (lane & 3) * 8;
    const u16* pA0 = A  + (size_t)(row0 + wave * 16 + lrow) * K + kbeg + lcol;  // rows 0..127
    const u16* pA1 = pA0 + (size_t)128 * K;                                     // rows 128..255
    const u16* pB0 = Bt + (size_t)(col0 + wave * 16 + lrow) * K + kbeg + lcol;  // rows 0..127
    u16* lA0 = &As[wave * 512];
    u16* lA1 = &As[4096 + wave * 512];
    u16* lB0 = &Bs[wave * 512];

    int wm = (wave >> 1) * 64, wn = (wave & 1) * 64;
    int quad = lane >> 4, l16 = lane & 15;

    f32x4_t acc[4][4];
#pragma unroll
    for (int i = 0; i < 4; i++)
#pragma unroll
        for (int j = 0; j < 4; j++) acc[i][j] = f32x4_t{0.f, 0.f, 0.f, 0.f};

    for (int kk = 0; kk < kchunk; kk += 64) {
        __syncthreads();
        g2l16(pA0, lA0);           g2l16(pA1, lA1);
        g2l16(pA0 + 32, lA0 + 8192); g2l16(pA1 + 32, lA1 + 8192);
        g2l16(pB0, lB0);           g2l16(pB0 + 32, lB0 + 4096);
        pA0 += 64; pA1 += 64; pB0 += 64;
        __syncthreads();

#pragma unroll
        for (int s = 0; s < 2; ++s) {
            const u16* as = &As[s * 8192];
            const u16* bs = &Bs[s * 4096];
            bf16x8_t a[4], b[4];
#pragma unroll
            for (int i = 0; i < 4; ++i)
                a[i] = *(const bf16x8_t*)&as[(wm + i * 16 + l16) * 32 + quad * 8];
#pragma unroll
            for (int j = 0; j < 4; ++j)
                b[j] = *(const bf16x8_t*)&bs[(wn + j * 16 + l16) * 32 + quad * 8];
#pragma unroll
            for (int i = 0; i < 4; ++i)
#pragma unroll
                for (int j = 0; j < 4; ++j)
                    acc[i][j] = __builtin_amdgcn_mfma_f32_16x16x32_bf16(a[i], b[j], acc[i][j], 0, 0, 0);
        }
    }

#pragma unroll
    for (int i = 0; i < 4; ++i)
#pragma unroll
        for (int j = 0; j < 4; ++j)
#pragma unroll
            for (int r = 0; r < 4; ++r) {
                int row = row0 + wm + i * 16 + quad * 4 + r;
                int col = col0 + wn + j * 16 + l16;
                float v = acc[i][j][r];
                if (EPI == 0) {
                    ((__half*)out)[(size_t)z * M * N + (size_t)row * N + col] = __float2half(v);
                } else {
                    ((u16*)out)[(size_t)row * N + col] = f2bf(fmaxf(v + bias0[col], 0.f));
                }
            }
}

// ================= QKV GEMM (128x128, 256 thr, 4 waves) =================
// Grid 24x32 = 768 blocks = 3/CU EVEN (fixes the 384-block 1.5/CU ragged dispatch).
// Q/K blocks: direct per-element scatter to [bh][s][dk].
// V blocks: whole-tile transposed restage (tile[c][r], LD=136) -> vectorized row reads
//           -> VT[bh][dk][s]. Coverage: 256 thr x 8 uint4 x 16B = 32KB = full 128x128 tile.
__global__ __launch_bounds__(256, 4)
void k_gemm_qkv(const u16* __restrict__ A, const u16* __restrict__ Bt,
                const float* __restrict__ bq, const float* __restrict__ bk,
                const float* __restrict__ bv, u16* __restrict__ QK,
                u16* __restrict__ VT, int M, int N, int K)
{
    __shared__ __align__(16) char pool[34816];     // K-loop: As 16KB + Bs 16KB; epi: tile[128][136]
    u16* As = (u16*)pool;
    u16* Bs = (u16*)(pool + 16384);

    int tid = threadIdx.x;
    int wave = tid >> 6, lane = tid & 63;

    // XCD-chunked bijective swizzle (nwg = 768, 768 % 8 == 0)
    int nx = gridDim.x, nwg = nx * gridDim.y;
    int f  = blockIdx.x + nx * blockIdx.y;
    int f2 = (f & 7) * (nwg >> 3) + (f >> 3);
    int bx = f2 % nx, by = f2 / nx;
    int row0 = by * 128, col0 = bx * 128;

    int lrow = lane >> 2, lcol = (lane & 3) * 8;
    const u16* pA0 = A  + (size_t)(row0 + wave * 16 + lrow) * K + lcol;
    const u16* pA1 = pA0 + (size_t)64 * K;
    const u16* pB0 = Bt + (size_t)(col0 + wave * 16 + lrow) * K + lcol;
    const u16* pB1 = pB0 + (size_t)64 * K;
    u16* lA0 = As + wave * 512;
    u16* lA1 = As + 2048 + wave * 512;
    u16* lB0 = Bs + wave * 512;
    u16* lB1 = Bs + 2048 + wave * 512;

    int wm = (wave >> 1) * 64, wn = (wave & 1) * 64;
    int quad = lane >> 4, l16 = lane & 15;

    f32x4_t acc[4][4];
#pragma unroll
    for (int i = 0; i < 4; i++)
#pragma unroll
        for (int j = 0; j < 4; j++) acc[i][j] = f32x4_t{0.f, 0.f, 0.f, 0.f};

    for (int kk = 0; kk < K; kk += 64) {
        __syncthreads();
        g2l16(pA0, lA0);      g2l16(pA1, lA1);
        g2l16(pA0 + 32, lA0 + 4096); g2l16(pA1 + 32, lA1 + 4096);
        g2l16(pB0, lB0);      g2l16(pB1, lB1);
        g2l16(pB0 + 32, lB0 + 4096); g2l16(pB1 + 32, lB1 + 4096);
        pA0 += 64; pA1 += 64; pB0 += 64; pB1 += 64;
        __syncthreads();

#pragma unroll
        for (int s = 0; s < 2; ++s) {
            const u16* as = As + s * 4096;
            const u16* bs = Bs + s * 4096;
            bf16x8_t a[4], b[4];
#pragma unroll
            for (int i = 0; i < 4; ++i)
                a[i] = *(const bf16x8_t*)(as + (wm + i * 16 + l16) * 32 + quad * 8);
#pragma unroll
            for (int j = 0; j < 4; ++j)
                b[j] = *(const bf16x8_t*)(bs + (wn + j * 16 + l16) * 32 + quad * 8);
#pragma unroll
            for (int i = 0; i < 4; ++i)
#pragma unroll
                for (int j = 0; j < 4; ++j)
                    acc[i][j] = __builtin_amdgcn_mfma_f32_16x16x32_bf16(a[i], b[j], acc[i][j], 0, 0, 0);
        }
    }

    int proj = col0 >> 10;                    // uniform per block (1024 % 128 == 0)
    int h0   = (col0 & 1023) >> 6;            // first of 2 heads in this tile
    int b_   = row0 >> 10, sb = row0 & 1023;  // batch, s-base (128-row slab)

    if (proj < 2) {
        // ---- Q/K: direct scatter (32B-granular; no LDS, no barriers) ----
        const float* bp = proj == 0 ? bq : bk;
        float scale = proj == 0 ? 0.18033688f : 1.f;   // 0.125 * log2(e)
        u16* dstbase = QK + (size_t)proj * 4194304;
#pragma unroll
        for (int i = 0; i < 4; ++i)
#pragma unroll
            for (int j = 0; j < 4; ++j)
#pragma unroll
                for (int r = 0; r < 4; ++r) {
                    int row = row0 + wm + i * 16 + quad * 4 + r;
                    int col = col0 + wn + j * 16 + l16;
                    int within = col & 1023;
                    float v = (acc[i][j][r] + bp[within]) * scale;
                    int h = within >> 6, kq = within & 63;
                    int s_ = row & 1023;
                    size_t bh = (size_t)((b_ << 4) + h);
                    dstbase[bh * 65536 + ((size_t)s_ << 6) + kq] = f2bf(v);
                }
    } else {
        // ---- V: whole-tile transposed restage -> coalesced VT ----
        u16* tile = (u16*)pool;               // tile[c(128)][r(128)] LD=136, 34816B
        __syncthreads();                      // retire K-loop LDS
#pragma unroll
        for (int i = 0; i < 4; ++i)
#pragma unroll
            for (int j = 0; j < 4; ++j) {
                int c = wn + j * 16 + l16;
                int bcol = (col0 & 1023) + c;
#pragma unroll
                for (int r = 0; r < 4; ++r)
                    tile[c * 136 + wm + i * 16 + quad * 4 + r] =
                        f2bf(acc[i][j][r] + bv[bcol]);
            }
        __syncthreads();
        // row reads: 8 consecutive uint4 per thread (256*8*16B = 32KB full coverage)
        int c = tid >> 1, v0 = (tid & 1) * 8;  // c in 0..127, slots v0..v0+7 of 16
        int head = c >> 6, kq = c & 63;
        size_t bh = (size_t)(b_ * 16 + h0 + head);
        u16* vb = VT + bh * 65536 + (size_t)kq * 1024 + sb;
#pragma unroll
        for (int k = 0; k < 8; ++k) {
            uint4 x = *(const uint4*)&tile[c * 136 + (v0 + k) * 8];
            *(uint4*)&vb[(v0 + k) * 8] = x;
        }
    }
}

// distinct-named wrappers for profiler decomposition (XCD-swizzled: nwg%8==0)
__global__ __launch_bounds__(512, 4)
void k_gemm_ffn1(const u16* __restrict__ A, const u16* __restrict__ Bt,
                 const float* __restrict__ b1, void* __restrict__ out,
                 int M, int N, int K)
{
    int nx = gridDim.x, nwg = nx * gridDim.y;
    int f  = blockIdx.x + nx * blockIdx.y;
    int f2 = (f & 7) * (nwg >> 3) + (f >> 3);
    gemm256x128<1>(A, Bt, b1, out, M, N, K, K, 0, f2 % nx, f2 / nx);
}

// FFN2: split-K=4, fp16 partials, XCD-chunked bijective swizzle within each z-slice
__global__ __launch_bounds__(512, 4)
void k_gemm_ffn2(const u16* __restrict__ A, const u16* __restrict__ Bt,
                 void* __restrict__ out, int M, int N, int K, int kchunk)
{
    int nx = gridDim.x, nwg = nx * gridDim.y;
    int f  = blockIdx.x + nx * blockIdx.y;
    int f2 = (f & 7) * (nwg >> 3) + (f >> 3);
    gemm256x128<0>(A, Bt, nullptr, out, M, N, K, kchunk, blockIdx.z, f2 % nx, f2 / nx);
}

// ---------------- flash attention v3: dbuf K/V, single barrier/tile, setprio ----------------
__global__ __launch_bounds__(512, 4)
void k_attn(const u16* __restrict__ Qg, const u16* __restrict__ Kg,
            const u16* __restrict__ VTg, u16* __restrict__ Og)
{
    __shared__ __align__(16) u16 Ks[2][64 * 64];
    __shared__ __align__(16) u16 Vs[2][64 * 64];
    __shared__ __align__(16) u16 Ps[128 * 64];

    int tid = threadIdx.x, wave = tid >> 6, lane = tid & 63;
    int quad = lane >> 4, l16 = lane & 15;

    int f  = blockIdx.x + gridDim.x * blockIdx.y;
    int f2 = (f & 7) * ((gridDim.x * gridDim.y) >> 3) + (f >> 3);
    int bh = f2 >> 3;
    int q0 = (f2 & 7) * 128;
    int wrow = wave * 16;

    const u16* Qp  = Qg  + (size_t)bh * 65536;
    const u16* Kp  = Kg  + (size_t)bh * 65536;
    const u16* VTp = VTg + (size_t)bh * 65536;

    int arow_g = q0 + wrow + l16;
    bf16x8_t aq0 = *(const bf16x8_t*)&Qp[(size_t)arow_g * 64 + quad * 8];
    bf16x8_t aq1 = *(const bf16x8_t*)&Qp[(size_t)arow_g * 64 + 32 + quad * 8];

    int srow = tid >> 3, scb = tid & 7;
    int sdoff = srow * 64 + ((scb ^ (srow & 7)) * 8);

    uint4 kreg = *(const uint4*)&Kp[(size_t)srow * 64 + scb * 8];
    uint4 vreg = *(const uint4*)&VTp[(size_t)srow * 1024 + scb * 8];

    f32x4_t o[4], lsum;
#pragma unroll
    for (int nt = 0; nt < 4; ++nt) o[nt] = f32x4_t{0.f, 0.f, 0.f, 0.f};
    lsum = f32x4_t{0.f, 0.f, 0.f, 0.f};

    bf16x8_t ones;
#pragma unroll
    for (int j = 0; j < 8; ++j) ones[j] = (short)0x3F80;

    int a7 = l16 & 7;

    *(uint4*)&Ks[0][sdoff] = kreg;
    *(uint4*)&Vs[0][sdoff] = vreg;
    kreg = *(const uint4*)&Kp[(size_t)(64 + srow) * 64 + scb * 8];
    vreg = *(const uint4*)&VTp[(size_t)srow * 1024 + 64 + scb * 8];
    __syncthreads();

    for (int t = 0; t < 16; ++t) {
        int cur = t & 1, nxt = cur ^ 1;
        if (t < 15) {
            *(uint4*)&Ks[nxt][sdoff] = kreg;
            *(uint4*)&Vs[nxt][sdoff] = vreg;
        }
        if (t < 14) {
            kreg = *(const uint4*)&Kp[(size_t)((t + 2) * 64 + srow) * 64 + scb * 8];
            vreg = *(const uint4*)&VTp[(size_t)srow * 1024 + (t + 2) * 64 + scb * 8];
        }

        f32x4_t s[4];
        __builtin_amdgcn_s_setprio(1);
#pragma unroll
        for (int nt = 0; nt < 4; ++nt) {
            int brow = nt * 16 + l16;
            bf16x8_t bk0 = *(const bf16x8_t*)&Ks[cur][brow * 64 + ((quad ^ a7) * 8)];
            bf16x8_t bk1 = *(const bf16x8_t*)&Ks[cur][brow * 64 + (((4 + quad) ^ a7) * 8)];
            s[nt] = __builtin_amdgcn_mfma_f32_16x16x32_bf16(aq0, bk0, f32x4_t{0.f,0.f,0.f,0.f}, 0, 0, 0);
            s[nt] = __builtin_amdgcn_mfma_f32_16x16x32_bf16(aq1, bk1, s[nt], 0, 0, 0);
        }
        __builtin_amdgcn_s_setprio(0);

#pragma unroll
        for (int nt = 0; nt < 4; ++nt) {
            int pcb = nt * 2 + (l16 >> 3);
#pragma unroll
            for (int r = 0; r < 4; ++r) {
                float p = exp2f(s[nt][r]);
                int pr = wrow + quad * 4 + r;
                Ps[pr * 64 + ((pcb ^ (pr & 7)) * 8) + (l16 & 7)] = f2bf(p);
            }
        }

        int arow = wrow + l16;
        bf16x8_t ap0 = *(const bf16x8_t*)&Ps[arow * 64 + ((quad ^ a7) * 8)];
        bf16x8_t ap1 = *(const bf16x8_t*)&Ps[arow * 64 + (((4 + quad) ^ a7) * 8)];
        __builtin_amdgcn_s_setprio(1);
#pragma unroll
        for (int nt = 0; nt < 4; ++nt) {
            int vrow = nt * 16 + l16;
            bf16x8_t bv0 = *(const bf16x8_t*)&Vs[cur][vrow * 64 + ((quad ^ a7) * 8)];
            bf16x8_t bv1 = *(const bf16x8_t*)&Vs[cur][vrow * 64 + (((4 + quad) ^ a7) * 8)];
            o[nt] = __builtin_amdgcn_mfma_f32_16x16x32_bf16(ap0, bv0, o[nt], 0, 0, 0);
            o[nt] = __builtin_amdgcn_mfma_f32_16x16x32_bf16(ap1, bv1, o[nt], 0, 0, 0);
        }
        lsum = __builtin_amdgcn_mfma_f32_16x16x32_bf16(ap0, ones, lsum, 0, 0, 0);
        lsum = __builtin_amdgcn_mfma_f32_16x16x32_bf16(ap1, ones, lsum, 0, 0, 0);
        __builtin_amdgcn_s_setprio(0);
        __syncthreads();
    }

    int b = bh >> 4, h = bh & 15;
    float invl[4];
#pragma unroll
    for (int r = 0; r < 4; ++r) invl[r] = 1.f / lsum[r];
#pragma unroll
    for (int nt = 0; nt < 4; ++nt)
#pragma unroll
        for (int r = 0; r < 4; ++r) {
            int srow2 = q0 + wrow + quad * 4 + r;
            Og[(size_t)(b * 1024 + srow2) * 1024 + (h << 6) + nt * 16 + l16] = f2bf(o[nt][r] * invl[r]);
        }
}

// ---------------- LayerNorm over (sum of NP fp16 partials + bias) + residual ----------------
template<int MODE, int NP>
__global__ __launch_bounds__(256)
void k_ln2(const __half* __restrict__ p, const float* __restrict__ bias,
           const float* __restrict__ residf, const u16* __restrict__ residb,
           const float* __restrict__ g, const float* __restrict__ be,
           float* __restrict__ out, u16* __restrict__ outb)
{
    int row = blockIdx.x, tid = threadIdx.x;
    size_t base = (size_t)row * 1024;
    int c0 = tid * 4;
    float xv[4];
    {
        float4 b4 = *(const float4*)&bias[c0];
        xv[0] = b4.x; xv[1] = b4.y; xv[2] = b4.z; xv[3] = b4.w;
    }
#pragma unroll
    for (int z = 0; z < NP; ++z) {
        union { uint2 u; __half h[4]; } cv;
        cv.u = *(const uint2*)&p[(size_t)z * 4194304 + base + c0];
#pragma unroll
        for (int i = 0; i < 4; ++i) xv[i] += __half2float(cv.h[i]);
    }
    float s = 0.f, sq = 0.f;
#pragma unroll
    for (int i = 0; i < 4; ++i) { s += xv[i]; sq += xv[i] * xv[i]; }
#pragma unroll
    for (int off = 32; off; off >>= 1) { s += __shfl_down(s, off); sq += __shfl_down(sq, off); }
    __shared__ float ss[4], ssq[4];
    int wv = tid >> 6;
    if ((tid & 63) == 0) { ss[wv] = s; ssq[wv] = sq; }
    __syncthreads();
    s  = ss[0] + ss[1] + ss[2] + ss[3];
    sq = ssq[0] + ssq[1] + ssq[2] + ssq[3];
    float mean = s * (1.f / 1024.f);
    float var  = sq * (1.f / 1024.f) - mean * mean;
    float rstd = rsqrtf(var + 1e-5f);

    float4 g4  = *(const float4*)&g[c0];
    float4 be4 = *(const float4*)&be[c0];
    float gv[4] = {g4.x, g4.y, g4.z, g4.w};
    float bv[4] = {be4.x, be4.y, be4.z, be4.w};
    float rv[4];
    if (MODE == 0) {
        float4 r4 = *(const float4*)&residf[base + c0];
        rv[0] = r4.x; rv[1] = r4.y; rv[2] = r4.z; rv[3] = r4.w;
    } else {
        ushort4 rb = *(const ushort4*)&residb[base + c0];
        rv[0] = bf2f(rb.x); rv[1] = bf2f(rb.y); rv[2] = bf2f(rb.z); rv[3] = bf2f(rb.w);
    }
    float y[4];
#pragma unroll
    for (int i = 0; i < 4; ++i) y[i] = rv[i] + (xv[i] - mean) * rstd * gv[i] + bv[i];
    if (MODE == 0) {
        ushort4 o;
        o.x = f2bf(y[0]); o.y = f2bf(y[1]); o.z = f2bf(y[2]); o.w = f2bf(y[3]);
        *(ushort4*)&outb[base + c0] = o;
    } else {
        float4 o; o.x = y[0]; o.y = y[1]; o.z = y[2]; o.w = y[3];
        *(float4*)&out[base + c0] = o;
    }
}

extern "C" void kernel_launch(void* const* d_in, const int* in_sizes, int n_in,
                              void* d_out, int out_size, void* d_ws, size_t ws_size,
                              hipStream_t stream) {
    const float* x   = (const float*)d_in[0];
    const float* Wq  = (const float*)d_in[1];
    const float* bq  = (const float*)d_in[2];
    const float* Wk  = (const float*)d_in[3];
    const float* bk  = (const float*)d_in[4];
    const float* Wv  = (const float*)d_in[5];
    const float* bv  = (const float*)d_in[6];
    const float* Wo  = (const float*)d_in[7];
    const float* bo  = (const float*)d_in[8];
    const float* W1  = (const float*)d_in[9];
    const float* b1  = (const float*)d_in[10];
    const float* W2  = (const float*)d_in[11];
    const float* b2  = (const float*)d_in[12];
    const float* g1  = (const float*)d_in[13];
    const float* be1 = (const float*)d_in[14];
    const float* g2  = (const float*)d_in[15];
    const float* be2 = (const float*)d_in[16];
    float* out = (float*)d_out;

    char* w = (char*)d_ws;
    u16*    Xb    = (u16*)(w);                    //  8 MB bf16 x (A operand; live through QKV)
    u16*    Wqkvt = (u16*)(w + 8388608);          //  6 MB [3072,1024] B^T
    u16*    Wot   = (u16*)(w + 14680064);         //  2 MB
    u16*    W1t   = (u16*)(w + 16777216);         //  8 MB
    u16*    W2t   = (u16*)(w + 25165824);         //  8 MB
    u16*    Qb    = (u16*)(w + 33554432);         //  8 MB [BH,S,DK] (K at +8MB)
    u16*    VTb   = (u16*)(w + 50331648);         //  8 MB [BH,DK,S] written by QKV epilogue
    u16*    Oc    = (u16*)(w + 58720256);         //  8 MB [4096,1024]
    __half* part4 = (__half*)(w + 33554432);      // 32 MB FFN2 split-K=4 fp16 partials (dead Q/K/VT/Oc)
    __half* part2 = (__half*)(w + 67108864);      // 16 MB O-proj split-K=2 fp16 partials
    u16*    x1b   = (u16*)(w + 117440512);        //  8 MB
    u16*    hb    = (u16*)(w + 125829120);        // 32 MB [4096,4096]

    // merged cast + all weight transposes (one launch)
    k_prep<<<7168, 256, 0, stream>>>(x, Xb, Wq, Wk, Wv, Wqkvt, Wo, W1, W2, Wot, W1t, W2t);

    // fused QKV projection (128x128, 768 blocks = 3/CU even); V written directly transposed
    k_gemm_qkv<<<dim3(24, 32), 256, 0, stream>>>(Xb, Wqkvt, bq, bk, bv, Qb, VTb, 4096, 3072, 1024);

    // flash attention v3 (dbuf K/V single-barrier)
    k_attn<<<dim3(8, 64), 512, 0, stream>>>(Qb, Qb + 4194304, VTb, Oc);

    // output projection, split-K=2, fp16 partials (128x128 kernel)
    k_gemm_bt<<<dim3(8, 32, 2), 256, 0, stream>>>(Oc, Wot, part2, 4096, 1024, 1024, 512);

    // x1b = bf16(x + LN(part0+part1+bo))
    k_ln2<0, 2><<<4096, 256, 0, stream>>>(part2, bo, x, nullptr, g1, be1, nullptr, x1b);

    // FFN1 (256x128 tile, 2-phase, XCD-swizzled): hb = relu(x1b @ W1 + b1)
    k_gemm_ffn1<<<dim3(32, 16), 512, 0, stream>>>(x1b, W1t, b1, hb, 4096, 4096, 1024);

    // FFN2 (256x128 tile, 2-phase), split-K=4, fp16 partials
    k_gemm_ffn2<<<dim3(8, 16, 4), 512, 0, stream>>>(hb, W2t, part4, 4096, 1024, 4096, 1024);

    // out = x1b + LN(part0..3 + b2)
    k_ln2<1, 4><<<4096, 256, 0, stream>>>(part4, b2, nullptr, x1b, g2, be2, out, nullptr);
}

// Round 11
// 302.764 us; speedup vs baseline: 1.0110x; 1.0027x over previous
//
#include <hip/hip_runtime.h>
#include <hip/hip_bf16.h>
#include <hip/hip_fp16.h>

typedef unsigned short u16;
typedef short bf16x8_t __attribute__((ext_vector_type(8)));
typedef float f32x4_t  __attribute__((ext_vector_type(4)));

__device__ __forceinline__ u16 f2bf(float f) {
    __hip_bfloat16 h = __float2bfloat16(f);
    union { __hip_bfloat16 b; u16 u; } cv; cv.b = h; return cv.u;
}

__device__ __forceinline__ float bf2f(u16 u) {
    union { unsigned int w; float f; } cv; cv.w = (unsigned int)u << 16; return cv.f;
}

// async global->LDS, 16B per lane; lds dest = wave-uniform base + lane*16
__device__ __forceinline__ void g2l16(const void* g, void* l) {
    __builtin_amdgcn_global_load_lds(
        (const __attribute__((address_space(1))) unsigned int*)g,
        (__attribute__((address_space(3))) unsigned int*)l, 16, 0, 0);
}

// ---------------- merged preprocessing: cast + Wqkv transpose + Wo/W1/W2 transpose ----------------
__global__ __launch_bounds__(256)
void k_prep(const float* __restrict__ x, u16* __restrict__ Xb,
            const float* __restrict__ Wq, const float* __restrict__ Wk,
            const float* __restrict__ Wv, u16* __restrict__ Wqkvt,
            const float* __restrict__ Wo, const float* __restrict__ W1,
            const float* __restrict__ W2, u16* __restrict__ Wot,
            u16* __restrict__ W1t, u16* __restrict__ W2t)
{
    int id = blockIdx.x;
    if (id < 4096) {                                   // cast branch (whole block)
        int i = id * 256 + threadIdx.x;
        float4 f = ((const float4*)x)[i];
        ushort4 o;
        o.x = f2bf(f.x); o.y = f2bf(f.y); o.z = f2bf(f.z); o.w = f2bf(f.w);
        ((ushort4*)Xb)[i] = o;
        return;
    }
    id -= 4096;
    const float* in; u16* out; int R, C, r0, c0;       // in [R][C] -> out [C][R]
    if (id < 768) {                                    // qkvw: id = tx + 16*head + 256*proj
        int zx = id >> 8, hy = (id >> 4) & 15, tx = id & 15;
        in  = (zx == 0 ? Wq : (zx == 1 ? Wk : Wv)) + (size_t)hy * 65536;
        out = Wqkvt + ((size_t)zx * 1024 + hy * 64) * 1024;
        R = 1024; C = 64; r0 = tx * 64; c0 = 0;
    } else {
        id -= 768;
        int tx, ty;
        if (id < 256)       { in = Wo; out = Wot; R = 1024; C = 1024; tx = id & 15; ty = id >> 4; }
        else if (id < 1280) { id -= 256; in = W1; out = W1t; R = 1024; C = 4096; tx = id & 63; ty = id >> 6; }
        else                { id -= 1280; in = W2; out = W2t; R = 4096; C = 1024; tx = id & 15; ty = id >> 4; }
        r0 = ty * 64; c0 = tx * 64;
    }
    __shared__ float t[64][65];
    int lc = threadIdx.x & 63, lr = threadIdx.x >> 6;
#pragma unroll
    for (int p = 0; p < 16; ++p) {
        int rr = p * 4 + lr;
        t[rr][lc] = in[(size_t)(r0 + rr) * C + c0 + lc];
    }
    __syncthreads();
#pragma unroll
    for (int p = 0; p < 16; ++p) {
        int cc = p * 4 + lr;
        out[(size_t)(c0 + cc) * R + r0 + lc] = f2bf(t[lc][cc]);
    }
}

// ---------------- 128x128 bf16 GEMM, split-K -> fp16 partials (O-proj) ----------------
__global__ __launch_bounds__(256, 4)
void k_gemm_bt(const u16* __restrict__ A, const u16* __restrict__ Bt,
               void* __restrict__ out, int M, int N, int K, int kchunk)
{
    __shared__ __align__(16) u16 As[2 * 128 * 32];
    __shared__ __align__(16) u16 Bs[2 * 128 * 32];
    int tid = threadIdx.x;
    int wave = tid >> 6, lane = tid & 63;

    int nx = gridDim.x, nwg = nx * gridDim.y;
    int f  = blockIdx.x + nx * blockIdx.y;
    int f2 = (f & 7) * (nwg >> 3) + (f >> 3);
    int bx = f2 % nx, by = f2 / nx;
    int row0 = by * 128, col0 = bx * 128;

    int z = blockIdx.z;
    int kbeg = z * kchunk;

    int lrow = lane >> 2, lcol = (lane & 3) * 8;
    const u16* pA0 = A  + (size_t)(row0 + wave * 16 + lrow) * K + kbeg + lcol;
    const u16* pA1 = pA0 + (size_t)64 * K;
    const u16* pB0 = Bt + (size_t)(col0 + wave * 16 + lrow) * K + kbeg + lcol;
    const u16* pB1 = pB0 + (size_t)64 * K;
    u16* lA0 = &As[wave * 512];
    u16* lA1 = &As[2048 + wave * 512];
    u16* lB0 = &Bs[wave * 512];
    u16* lB1 = &Bs[2048 + wave * 512];

    int wm = (wave >> 1) * 64, wn = (wave & 1) * 64;
    int quad = lane >> 4, l16 = lane & 15;

    f32x4_t acc[4][4];
#pragma unroll
    for (int i = 0; i < 4; i++)
#pragma unroll
        for (int j = 0; j < 4; j++) acc[i][j] = f32x4_t{0.f, 0.f, 0.f, 0.f};

    for (int kk = 0; kk < kchunk; kk += 64) {
        __syncthreads();
        g2l16(pA0, lA0);      g2l16(pA1, lA1);
        g2l16(pA0 + 32, lA0 + 4096); g2l16(pA1 + 32, lA1 + 4096);
        g2l16(pB0, lB0);      g2l16(pB1, lB1);
        g2l16(pB0 + 32, lB0 + 4096); g2l16(pB1 + 32, lB1 + 4096);
        pA0 += 64; pA1 += 64; pB0 += 64; pB1 += 64;
        __syncthreads();

#pragma unroll
        for (int s = 0; s < 2; ++s) {
            const u16* as = &As[s * 4096];
            const u16* bs = &Bs[s * 4096];
            bf16x8_t a[4], b[4];
#pragma unroll
            for (int i = 0; i < 4; ++i)
                a[i] = *(const bf16x8_t*)&as[(wm + i * 16 + l16) * 32 + quad * 8];
#pragma unroll
            for (int j = 0; j < 4; ++j)
                b[j] = *(const bf16x8_t*)&bs[(wn + j * 16 + l16) * 32 + quad * 8];
#pragma unroll
            for (int i = 0; i < 4; ++i)
#pragma unroll
                for (int j = 0; j < 4; ++j)
                    acc[i][j] = __builtin_amdgcn_mfma_f32_16x16x32_bf16(a[i], b[j], acc[i][j], 0, 0, 0);
        }
    }

#pragma unroll
    for (int i = 0; i < 4; ++i)
#pragma unroll
        for (int j = 0; j < 4; ++j)
#pragma unroll
            for (int r = 0; r < 4; ++r) {
                int row = row0 + wm + i * 16 + quad * 4 + r;
                int col = col0 + wn + j * 16 + l16;
                ((__half*)out)[(size_t)z * M * N + (size_t)row * N + col] =
                    __float2half(acc[i][j][r]);
            }
}

// ================= common 256x128 bf16 GEMM body (2-phase, 512 thr, 8 waves) =================
// EPI 0: fp16 split-K partial; EPI 1: relu+bias bf16
template<int EPI>
__device__ __forceinline__
void gemm256x128(const u16* __restrict__ A, const u16* __restrict__ Bt,
                 const float* __restrict__ bias0, void* __restrict__ out,
                 int M, int N, int K, int kchunk, int z, int bx, int by)
{
    __shared__ __align__(16) u16 As[2 * 256 * 32];   // 2 subtiles of [256][32]
    __shared__ __align__(16) u16 Bs[2 * 128 * 32];   // 2 subtiles of [128][32]
    int tid = threadIdx.x;
    int wave = tid >> 6, lane = tid & 63;
    int row0 = by * 256, col0 = bx * 128;
    int kbeg = z * kchunk;

    int lrow = lane >> 2, lcol = (lane & 3) * 8;
    const u16* pA0 = A  + (size_t)(row0 + wave * 16 + lrow) * K + kbeg + lcol;  // rows 0..127
    const u16* pA1 = pA0 + (size_t)128 * K;                                     // rows 128..255
    const u16* pB0 = Bt + (size_t)(col0 + wave * 16 + lrow) * K + kbeg + lcol;  // rows 0..127
    u16* lA0 = &As[wave * 512];
    u16* lA1 = &As[4096 + wave * 512];
    u16* lB0 = &Bs[wave * 512];

    int wm = (wave >> 1) * 64, wn = (wave & 1) * 64;
    int quad = lane >> 4, l16 = lane & 15;

    f32x4_t acc[4][4];
#pragma unroll
    for (int i = 0; i < 4; i++)
#pragma unroll
        for (int j = 0; j < 4; j++) acc[i][j] = f32x4_t{0.f, 0.f, 0.f, 0.f};

    for (int kk = 0; kk < kchunk; kk += 64) {
        __syncthreads();
        g2l16(pA0, lA0);           g2l16(pA1, lA1);
        g2l16(pA0 + 32, lA0 + 8192); g2l16(pA1 + 32, lA1 + 8192);
        g2l16(pB0, lB0);           g2l16(pB0 + 32, lB0 + 4096);
        pA0 += 64; pA1 += 64; pB0 += 64;
        __syncthreads();

#pragma unroll
        for (int s = 0; s < 2; ++s) {
            const u16* as = &As[s * 8192];
            const u16* bs = &Bs[s * 4096];
            bf16x8_t a[4], b[4];
#pragma unroll
            for (int i = 0; i < 4; ++i)
                a[i] = *(const bf16x8_t*)&as[(wm + i * 16 + l16) * 32 + quad * 8];
#pragma unroll
            for (int j = 0; j < 4; ++j)
                b[j] = *(const bf16x8_t*)&bs[(wn + j * 16 + l16) * 32 + quad * 8];
#pragma unroll
            for (int i = 0; i < 4; ++i)
#pragma unroll
                for (int j = 0; j < 4; ++j)
                    acc[i][j] = __builtin_amdgcn_mfma_f32_16x16x32_bf16(a[i], b[j], acc[i][j], 0, 0, 0);
        }
    }

#pragma unroll
    for (int i = 0; i < 4; ++i)
#pragma unroll
        for (int j = 0; j < 4; ++j)
#pragma unroll
            for (int r = 0; r < 4; ++r) {
                int row = row0 + wm + i * 16 + quad * 4 + r;
                int col = col0 + wn + j * 16 + l16;
                float v = acc[i][j][r];
                if (EPI == 0) {
                    ((__half*)out)[(size_t)z * M * N + (size_t)row * N + col] = __float2half(v);
                } else {
                    ((u16*)out)[(size_t)row * N + col] = f2bf(fmaxf(v + bias0[col], 0.f));
                }
            }
}

// ================= QKV GEMM (128x128, 256 thr, 4 waves) =================
// Grid 24x32 = 768 blocks = 3/CU EVEN.
// Q/K blocks: direct per-element scatter to [bh][s][dk].
// V blocks: whole-tile transposed restage (tile[c][r], LD=136) -> vectorized row reads
//           -> VT[bh][dk][s]. Coverage: 256 thr x 8 uint4 x 16B = 32KB = full 128x128 tile.
__global__ __launch_bounds__(256, 4)
void k_gemm_qkv(const u16* __restrict__ A, const u16* __restrict__ Bt,
                const float* __restrict__ bq, const float* __restrict__ bk,
                const float* __restrict__ bv, u16* __restrict__ QK,
                u16* __restrict__ VT, int M, int N, int K)
{
    __shared__ __align__(16) char pool[34816];     // K-loop: As 16KB + Bs 16KB; epi: tile[128][136]
    u16* As = (u16*)pool;
    u16* Bs = (u16*)(pool + 16384);

    int tid = threadIdx.x;
    int wave = tid >> 6, lane = tid & 63;

    // XCD-chunked bijective swizzle (nwg = 768, 768 % 8 == 0)
    int nx = gridDim.x, nwg = nx * gridDim.y;
    int f  = blockIdx.x + nx * blockIdx.y;
    int f2 = (f & 7) * (nwg >> 3) + (f >> 3);
    int bx = f2 % nx, by = f2 / nx;
    int row0 = by * 128, col0 = bx * 128;

    int lrow = lane >> 2, lcol = (lane & 3) * 8;
    const u16* pA0 = A  + (size_t)(row0 + wave * 16 + lrow) * K + lcol;
    const u16* pA1 = pA0 + (size_t)64 * K;
    const u16* pB0 = Bt + (size_t)(col0 + wave * 16 + lrow) * K + lcol;
    const u16* pB1 = pB0 + (size_t)64 * K;
    u16* lA0 = As + wave * 512;
    u16* lA1 = As + 2048 + wave * 512;
    u16* lB0 = Bs + wave * 512;
    u16* lB1 = Bs + 2048 + wave * 512;

    int wm = (wave >> 1) * 64, wn = (wave & 1) * 64;
    int quad = lane >> 4, l16 = lane & 15;

    f32x4_t acc[4][4];
#pragma unroll
    for (int i = 0; i < 4; i++)
#pragma unroll
        for (int j = 0; j < 4; j++) acc[i][j] = f32x4_t{0.f, 0.f, 0.f, 0.f};

    for (int kk = 0; kk < K; kk += 64) {
        __syncthreads();
        g2l16(pA0, lA0);      g2l16(pA1, lA1);
        g2l16(pA0 + 32, lA0 + 4096); g2l16(pA1 + 32, lA1 + 4096);
        g2l16(pB0, lB0);      g2l16(pB1, lB1);
        g2l16(pB0 + 32, lB0 + 4096); g2l16(pB1 + 32, lB1 + 4096);
        pA0 += 64; pA1 += 64; pB0 += 64; pB1 += 64;
        __syncthreads();

#pragma unroll
        for (int s = 0; s < 2; ++s) {
            const u16* as = As + s * 4096;
            const u16* bs = Bs + s * 4096;
            bf16x8_t a[4], b[4];
#pragma unroll
            for (int i = 0; i < 4; ++i)
                a[i] = *(const bf16x8_t*)(as + (wm + i * 16 + l16) * 32 + quad * 8);
#pragma unroll
            for (int j = 0; j < 4; ++j)
                b[j] = *(const bf16x8_t*)(bs + (wn + j * 16 + l16) * 32 + quad * 8);
#pragma unroll
            for (int i = 0; i < 4; ++i)
#pragma unroll
                for (int j = 0; j < 4; ++j)
                    acc[i][j] = __builtin_amdgcn_mfma_f32_16x16x32_bf16(a[i], b[j], acc[i][j], 0, 0, 0);
        }
    }

    int proj = col0 >> 10;                    // uniform per block (1024 % 128 == 0)
    int h0   = (col0 & 1023) >> 6;            // first of 2 heads in this tile
    int b_   = row0 >> 10, sb = row0 & 1023;  // batch, s-base (128-row slab)

    if (proj < 2) {
        // ---- Q/K: direct scatter (32B-granular; no LDS, no barriers) ----
        const float* bp = proj == 0 ? bq : bk;
        float scale = proj == 0 ? 0.18033688f : 1.f;   // 0.125 * log2(e)
        u16* dstbase = QK + (size_t)proj * 4194304;
#pragma unroll
        for (int i = 0; i < 4; ++i)
#pragma unroll
            for (int j = 0; j < 4; ++j)
#pragma unroll
                for (int r = 0; r < 4; ++r) {
                    int row = row0 + wm + i * 16 + quad * 4 + r;
                    int col = col0 + wn + j * 16 + l16;
                    int within = col & 1023;
                    float v = (acc[i][j][r] + bp[within]) * scale;
                    int h = within >> 6, kq = within & 63;
                    int s_ = row & 1023;
                    size_t bh = (size_t)((b_ << 4) + h);
                    dstbase[bh * 65536 + ((size_t)s_ << 6) + kq] = f2bf(v);
                }
    } else {
        // ---- V: whole-tile transposed restage -> coalesced VT ----
        u16* tile = (u16*)pool;               // tile[c(128)][r(128)] LD=136, 34816B
        __syncthreads();                      // retire K-loop LDS
#pragma unroll
        for (int i = 0; i < 4; ++i)
#pragma unroll
            for (int j = 0; j < 4; ++j) {
                int c = wn + j * 16 + l16;
                int bcol = (col0 & 1023) + c;
#pragma unroll
                for (int r = 0; r < 4; ++r)
                    tile[c * 136 + wm + i * 16 + quad * 4 + r] =
                        f2bf(acc[i][j][r] + bv[bcol]);
            }
        __syncthreads();
        // row reads: 8 consecutive uint4 per thread (256*8*16B = 32KB full coverage)
        int c = tid >> 1, v0 = (tid & 1) * 8;  // c in 0..127, slots v0..v0+7 of 16
        int head = c >> 6, kq = c & 63;
        size_t bh = (size_t)(b_ * 16 + h0 + head);
        u16* vb = VT + bh * 65536 + (size_t)kq * 1024 + sb;
#pragma unroll
        for (int k = 0; k < 8; ++k) {
            uint4 x = *(const uint4*)&tile[c * 136 + (v0 + k) * 8];
            *(uint4*)&vb[(v0 + k) * 8] = x;
        }
    }
}

// distinct-named wrappers for profiler decomposition (XCD-swizzled: nwg%8==0)
__global__ __launch_bounds__(512, 4)
void k_gemm_ffn1(const u16* __restrict__ A, const u16* __restrict__ Bt,
                 const float* __restrict__ b1, void* __restrict__ out,
                 int M, int N, int K)
{
    int nx = gridDim.x, nwg = nx * gridDim.y;
    int f  = blockIdx.x + nx * blockIdx.y;
    int f2 = (f & 7) * (nwg >> 3) + (f >> 3);
    gemm256x128<1>(A, Bt, b1, out, M, N, K, K, 0, f2 % nx, f2 / nx);
}

// FFN2: split-K=4, fp16 partials, XCD-chunked bijective swizzle within each z-slice
__global__ __launch_bounds__(512, 4)
void k_gemm_ffn2(const u16* __restrict__ A, const u16* __restrict__ Bt,
                 void* __restrict__ out, int M, int N, int K, int kchunk)
{
    int nx = gridDim.x, nwg = nx * gridDim.y;
    int f  = blockIdx.x + nx * blockIdx.y;
    int f2 = (f & 7) * (nwg >> 3) + (f >> 3);
    gemm256x128<0>(A, Bt, nullptr, out, M, N, K, kchunk, blockIdx.z, f2 % nx, f2 / nx);
}

// ---------------- flash attention v3: 4 waves x 32 q-rows (K/V LDS-read amortized 2x) ----------------
// attn is LDS-BW-bound (model: ~192KB/tile/block at 8x16-row waves). Each wave now owns 32 q-rows:
// bk/bv fragments read ONCE per wave and reused for both 16-row groups -> K/V frag reads halve.
// dbuf K/V single barrier/tile unchanged; staging covers 2 rows/thread (256 thr).
__global__ __launch_bounds__(256, 2)
void k_attn(const u16* __restrict__ Qg, const u16* __restrict__ Kg,
            const u16* __restrict__ VTg, u16* __restrict__ Og)
{
    __shared__ __align__(16) u16 Ks[2][64 * 64];
    __shared__ __align__(16) u16 Vs[2][64 * 64];
    __shared__ __align__(16) u16 Ps[128 * 64];

    int tid = threadIdx.x, wave = tid >> 6, lane = tid & 63;
    int quad = lane >> 4, l16 = lane & 15;

    int f  = blockIdx.x + gridDim.x * blockIdx.y;
    int f2 = (f & 7) * ((gridDim.x * gridDim.y) >> 3) + (f >> 3);
    int bh = f2 >> 3;
    int q0 = (f2 & 7) * 128;
    int wrow = wave * 32;                       // 4 waves x 32 rows

    const u16* Qp  = Qg  + (size_t)bh * 65536;
    const u16* Kp  = Kg  + (size_t)bh * 65536;
    const u16* VTp = VTg + (size_t)bh * 65536;

    bf16x8_t aq[2][2];
#pragma unroll
    for (int g = 0; g < 2; ++g) {
        int arow_g = q0 + wrow + g * 16 + l16;
        aq[g][0] = *(const bf16x8_t*)&Qp[(size_t)arow_g * 64 + quad * 8];
        aq[g][1] = *(const bf16x8_t*)&Qp[(size_t)arow_g * 64 + 32 + quad * 8];
    }

    // staging: 256 threads cover rows srow and srow+32 (2 uint4 each for K and V)
    int srow = tid >> 3, scb = tid & 7;          // srow 0..31
    int srow2 = srow + 32;
    int sdoff0 = srow  * 64 + ((scb ^ (srow  & 7)) * 8);
    int sdoff1 = srow2 * 64 + ((scb ^ (srow2 & 7)) * 8);

    uint4 kreg0 = *(const uint4*)&Kp[(size_t)srow  * 64 + scb * 8];
    uint4 kreg1 = *(const uint4*)&Kp[(size_t)srow2 * 64 + scb * 8];
    uint4 vreg0 = *(const uint4*)&VTp[(size_t)srow  * 1024 + scb * 8];
    uint4 vreg1 = *(const uint4*)&VTp[(size_t)srow2 * 1024 + scb * 8];

    f32x4_t o[2][4], lsum[2];
#pragma unroll
    for (int g = 0; g < 2; ++g) {
#pragma unroll
        for (int nt = 0; nt < 4; ++nt) o[g][nt] = f32x4_t{0.f, 0.f, 0.f, 0.f};
        lsum[g] = f32x4_t{0.f, 0.f, 0.f, 0.f};
    }

    bf16x8_t ones;
#pragma unroll
    for (int j = 0; j < 8; ++j) ones[j] = (short)0x3F80;

    int a7 = l16 & 7;

    *(uint4*)&Ks[0][sdoff0] = kreg0;  *(uint4*)&Ks[0][sdoff1] = kreg1;
    *(uint4*)&Vs[0][sdoff0] = vreg0;  *(uint4*)&Vs[0][sdoff1] = vreg1;
    kreg0 = *(const uint4*)&Kp[(size_t)(64 + srow ) * 64 + scb * 8];
    kreg1 = *(const uint4*)&Kp[(size_t)(64 + srow2) * 64 + scb * 8];
    vreg0 = *(const uint4*)&VTp[(size_t)srow  * 1024 + 64 + scb * 8];
    vreg1 = *(const uint4*)&VTp[(size_t)srow2 * 1024 + 64 + scb * 8];
    __syncthreads();

    for (int t = 0; t < 16; ++t) {
        int cur = t & 1, nxt = cur ^ 1;
        if (t < 15) {
            *(uint4*)&Ks[nxt][sdoff0] = kreg0;  *(uint4*)&Ks[nxt][sdoff1] = kreg1;
            *(uint4*)&Vs[nxt][sdoff0] = vreg0;  *(uint4*)&Vs[nxt][sdoff1] = vreg1;
        }
        if (t < 14) {
            kreg0 = *(const uint4*)&Kp[(size_t)((t + 2) * 64 + srow ) * 64 + scb * 8];
            kreg1 = *(const uint4*)&Kp[(size_t)((t + 2) * 64 + srow2) * 64 + scb * 8];
            vreg0 = *(const uint4*)&VTp[(size_t)srow  * 1024 + (t + 2) * 64 + scb * 8];
            vreg1 = *(const uint4*)&VTp[(size_t)srow2 * 1024 + (t + 2) * 64 + scb * 8];
        }

        // QK^T: bk fragments read once, reused for both q-groups
        f32x4_t s[2][4];
        __builtin_amdgcn_s_setprio(1);
#pragma unroll
        for (int nt = 0; nt < 4; ++nt) {
            int brow = nt * 16 + l16;
            bf16x8_t bk0 = *(const bf16x8_t*)&Ks[cur][brow * 64 + ((quad ^ a7) * 8)];
            bf16x8_t bk1 = *(const bf16x8_t*)&Ks[cur][brow * 64 + (((4 + quad) ^ a7) * 8)];
#pragma unroll
            for (int g = 0; g < 2; ++g) {
                s[g][nt] = __builtin_amdgcn_mfma_f32_16x16x32_bf16(aq[g][0], bk0, f32x4_t{0.f,0.f,0.f,0.f}, 0, 0, 0);
                s[g][nt] = __builtin_amdgcn_mfma_f32_16x16x32_bf16(aq[g][1], bk1, s[g][nt], 0, 0, 0);
            }
        }
        __builtin_amdgcn_s_setprio(0);

#pragma unroll
        for (int g = 0; g < 2; ++g)
#pragma unroll
            for (int nt = 0; nt < 4; ++nt) {
                int pcb = nt * 2 + (l16 >> 3);
#pragma unroll
                for (int r = 0; r < 4; ++r) {
                    float p = exp2f(s[g][nt][r]);
                    int pr = wrow + g * 16 + quad * 4 + r;
                    Ps[pr * 64 + ((pcb ^ (pr & 7)) * 8) + (l16 & 7)] = f2bf(p);
                }
            }

        bf16x8_t ap[2][2];
#pragma unroll
        for (int g = 0; g < 2; ++g) {
            int arow = wrow + g * 16 + l16;
            ap[g][0] = *(const bf16x8_t*)&Ps[arow * 64 + ((quad ^ a7) * 8)];
            ap[g][1] = *(const bf16x8_t*)&Ps[arow * 64 + (((4 + quad) ^ a7) * 8)];
        }
        // PV: bv fragments read once, reused for both q-groups
        __builtin_amdgcn_s_setprio(1);
#pragma unroll
        for (int nt = 0; nt < 4; ++nt) {
            int vrow = nt * 16 + l16;
            bf16x8_t bv0 = *(const bf16x8_t*)&Vs[cur][vrow * 64 + ((quad ^ a7) * 8)];
            bf16x8_t bv1 = *(const bf16x8_t*)&Vs[cur][vrow * 64 + (((4 + quad) ^ a7) * 8)];
#pragma unroll
            for (int g = 0; g < 2; ++g) {
                o[g][nt] = __builtin_amdgcn_mfma_f32_16x16x32_bf16(ap[g][0], bv0, o[g][nt], 0, 0, 0);
                o[g][nt] = __builtin_amdgcn_mfma_f32_16x16x32_bf16(ap[g][1], bv1, o[g][nt], 0, 0, 0);
            }
        }
#pragma unroll
        for (int g = 0; g < 2; ++g) {
            lsum[g] = __builtin_amdgcn_mfma_f32_16x16x32_bf16(ap[g][0], ones, lsum[g], 0, 0, 0);
            lsum[g] = __builtin_amdgcn_mfma_f32_16x16x32_bf16(ap[g][1], ones, lsum[g], 0, 0, 0);
        }
        __builtin_amdgcn_s_setprio(0);
        __syncthreads();
    }

    int b = bh >> 4, h = bh & 15;
#pragma unroll
    for (int g = 0; g < 2; ++g) {
        float invl[4];
#pragma unroll
        for (int r = 0; r < 4; ++r) invl[r] = 1.f / lsum[g][r];
#pragma unroll
        for (int nt = 0; nt < 4; ++nt)
#pragma unroll
            for (int r = 0; r < 4; ++r) {
                int srow_o = q0 + wrow + g * 16 + quad * 4 + r;
                Og[(size_t)(b * 1024 + srow_o) * 1024 + (h << 6) + nt * 16 + l16] =
                    f2bf(o[g][nt][r] * invl[r]);
            }
    }
}

// ---------------- LayerNorm over (sum of NP fp16 partials + bias) + residual ----------------
template<int MODE, int NP>
__global__ __launch_bounds__(256)
void k_ln2(const __half* __restrict__ p, const float* __restrict__ bias,
           const float* __restrict__ residf, const u16* __restrict__ residb,
           const float* __restrict__ g, const float* __restrict__ be,
           float* __restrict__ out, u16* __restrict__ outb)
{
    int row = blockIdx.x, tid = threadIdx.x;
    size_t base = (size_t)row * 1024;
    int c0 = tid * 4;
    float xv[4];
    {
        float4 b4 = *(const float4*)&bias[c0];
        xv[0] = b4.x; xv[1] = b4.y; xv[2] = b4.z; xv[3] = b4.w;
    }
#pragma unroll
    for (int z = 0; z < NP; ++z) {
        union { uint2 u; __half h[4]; } cv;
        cv.u = *(const uint2*)&p[(size_t)z * 4194304 + base + c0];
#pragma unroll
        for (int i = 0; i < 4; ++i) xv[i] += __half2float(cv.h[i]);
    }
    float s = 0.f, sq = 0.f;
#pragma unroll
    for (int i = 0; i < 4; ++i) { s += xv[i]; sq += xv[i] * xv[i]; }
#pragma unroll
    for (int off = 32; off; off >>= 1) { s += __shfl_down(s, off); sq += __shfl_down(sq, off); }
    __shared__ float ss[4], ssq[4];
    int wv = tid >> 6;
    if ((tid & 63) == 0) { ss[wv] = s; ssq[wv] = sq; }
    __syncthreads();
    s  = ss[0] + ss[1] + ss[2] + ss[3];
    sq = ssq[0] + ssq[1] + ssq[2] + ssq[3];
    float mean = s * (1.f / 1024.f);
    float var  = sq * (1.f / 1024.f) - mean * mean;
    float rstd = rsqrtf(var + 1e-5f);

    float4 g4  = *(const float4*)&g[c0];
    float4 be4 = *(const float4*)&be[c0];
    float gv[4] = {g4.x, g4.y, g4.z, g4.w};
    float bv[4] = {be4.x, be4.y, be4.z, be4.w};
    float rv[4];
    if (MODE == 0) {
        float4 r4 = *(const float4*)&residf[base + c0];
        rv[0] = r4.x; rv[1] = r4.y; rv[2] = r4.z; rv[3] = r4.w;
    } else {
        ushort4 rb = *(const ushort4*)&residb[base + c0];
        rv[0] = bf2f(rb.x); rv[1] = bf2f(rb.y); rv[2] = bf2f(rb.z); rv[3] = bf2f(rb.w);
    }
    float y[4];
#pragma unroll
    for (int i = 0; i < 4; ++i) y[i] = rv[i] + (xv[i] - mean) * rstd * gv[i] + bv[i];
    if (MODE == 0) {
        ushort4 o;
        o.x = f2bf(y[0]); o.y = f2bf(y[1]); o.z = f2bf(y[2]); o.w = f2bf(y[3]);
        *(ushort4*)&outb[base + c0] = o;
    } else {
        float4 o; o.x = y[0]; o.y = y[1]; o.z = y[2]; o.w = y[3];
        *(float4*)&out[base + c0] = o;
    }
}

extern "C" void kernel_launch(void* const* d_in, const int* in_sizes, int n_in,
                              void* d_out, int out_size, void* d_ws, size_t ws_size,
                              hipStream_t stream) {
    const float* x   = (const float*)d_in[0];
    const float* Wq  = (const float*)d_in[1];
    const float* bq  = (const float*)d_in[2];
    const float* Wk  = (const float*)d_in[3];
    const float* bk  = (const float*)d_in[4];
    const float* Wv  = (const float*)d_in[5];
    const float* bv  = (const float*)d_in[6];
    const float* Wo  = (const float*)d_in[7];
    const float* bo  = (const float*)d_in[8];
    const float* W1  = (const float*)d_in[9];
    const float* b1  = (const float*)d_in[10];
    const float* W2  = (const float*)d_in[11];
    const float* b2  = (const float*)d_in[12];
    const float* g1  = (const float*)d_in[13];
    const float* be1 = (const float*)d_in[14];
    const float* g2  = (const float*)d_in[15];
    const float* be2 = (const float*)d_in[16];
    float* out = (float*)d_out;

    char* w = (char*)d_ws;
    u16*    Xb    = (u16*)(w);                    //  8 MB bf16 x (A operand; live through QKV)
    u16*    Wqkvt = (u16*)(w + 8388608);          //  6 MB [3072,1024] B^T
    u16*    Wot   = (u16*)(w + 14680064);         //  2 MB
    u16*    W1t   = (u16*)(w + 16777216);         //  8 MB
    u16*    W2t   = (u16*)(w + 25165824);         //  8 MB
    u16*    Qb    = (u16*)(w + 33554432);         //  8 MB [BH,S,DK] (K at +8MB)
    u16*    VTb   = (u16*)(w + 50331648);         //  8 MB [BH,DK,S] written by QKV epilogue
    u16*    Oc    = (u16*)(w + 58720256);         //  8 MB [4096,1024]
    __half* part4 = (__half*)(w + 33554432);      // 32 MB FFN2 split-K=4 fp16 partials (dead Q/K/VT/Oc)
    __half* part2 = (__half*)(w + 67108864);      // 16 MB O-proj split-K=2 fp16 partials
    u16*    x1b   = (u16*)(w + 117440512);        //  8 MB
    u16*    hb    = (u16*)(w + 125829120);        // 32 MB [4096,4096]

    // merged cast + all weight transposes (one launch)
    k_prep<<<7168, 256, 0, stream>>>(x, Xb, Wq, Wk, Wv, Wqkvt, Wo, W1, W2, Wot, W1t, W2t);

    // fused QKV projection (128x128, 768 blocks = 3/CU even); V written directly transposed
    k_gemm_qkv<<<dim3(24, 32), 256, 0, stream>>>(Xb, Wqkvt, bq, bk, bv, Qb, VTb, 4096, 3072, 1024);

    // flash attention v3 (4 waves x 32 q-rows, dbuf K/V single-barrier)
    k_attn<<<dim3(8, 64), 256, 0, stream>>>(Qb, Qb + 4194304, VTb, Oc);

    // output projection, split-K=2, fp16 partials (128x128 kernel)
    k_gemm_bt<<<dim3(8, 32, 2), 256, 0, stream>>>(Oc, Wot, part2, 4096, 1024, 1024, 512);

    // x1b = bf16(x + LN(part0+part1+bo))
    k_ln2<0, 2><<<4096, 256, 0, stream>>>(part2, bo, x, nullptr, g1, be1, nullptr, x1b);

    // FFN1 (256x128 tile, 2-phase, XCD-swizzled): hb = relu(x1b @ W1 + b1)
    k_gemm_ffn1<<<dim3(32, 16), 512, 0, stream>>>(x1b, W1t, b1, hb, 4096, 4096, 1024);

    // FFN2 (256x128 tile, 2-phase), split-K=4, fp16 partials
    k_gemm_ffn2<<<dim3(8, 16, 4), 512, 0, stream>>>(hb, W2t, part4, 4096, 1024, 4096, 1024);

    // out = x1b + LN(part0..3 + b2)
    k_ln2<1, 4><<<4096, 256, 0, stream>>>(part4, b2, nullptr, x1b, g2, be2, out, nullptr);
}